// Round 7
// baseline (239.036 us; speedup 1.0000x reference)
//
#include <hip/hip_runtime.h>
#include <stdint.h>

// Problem constants (B=4, S=2048 -> M = 8192 rows)
#define M_TOT 8192
#define N_TOT 4096
#define K_TOT 4096

typedef int v4i __attribute__((ext_vector_type(4)));
typedef int v16i __attribute__((ext_vector_type(16)));

// GEMM tile config: 256x256 tile, sub-tile K-step = 64 B, 8 waves (2M x 4N)
#define BM 256
#define BN 256
#define SUB 64
#define NS (K_TOT / SUB)                  // 64 sub-tile iterations
#define A_SUB (BM * SUB)                  // 16 KB
#define B_SUB (BN * SUB)                  // 16 KB
#define BUF_BYTES (A_SUB + B_SUB)         // 32 KB; x4 buffers = 128 KB LDS

// ---------------------------------------------------------------------------
// Kernel 1: fused pre-pass: pack weight int32->int8 + global max(|x/smooth|).
// Grid stride (2048*256=524288) is a multiple of K/4=1024, so each thread's
// smooth slice index (g0 & 1023) is LOOP-INVARIANT -> hoist the load and the
// 4 divides out of the loop. Per-iter: 4 mul + 4 max-with-abs-modifier.
// ---------------------------------------------------------------------------
__global__ void prep_reduce(const int4* __restrict__ w32, int* __restrict__ w8,
                            int nw4, const float4* __restrict__ smooth4,
                            const float4* __restrict__ x,
                            unsigned int* __restrict__ maxbits, int nx4) {
  const int stride = gridDim.x * blockDim.x;
  const int g0 = blockIdx.x * blockDim.x + threadIdx.x;
  // pack weights
  for (int i = g0; i < nw4; i += stride) {
    int4 v = w32[i];
    w8[i] = (v.x & 0xff) | ((v.y & 0xff) << 8) | ((v.z & 0xff) << 16) | (v.w << 24);
  }
  // max-abs reduce with hoisted reciprocal
  float4 s = smooth4[g0 & (K_TOT / 4 - 1)];
  const float rx = 1.0f / s.x, ry = 1.0f / s.y, rz = 1.0f / s.z, rw = 1.0f / s.w;
  float m = 0.0f;
  for (int i = g0; i < nx4; i += stride) {
    float4 v = x[i];
    m = fmaxf(m, fabsf(v.x * rx));
    m = fmaxf(m, fabsf(v.y * ry));
    m = fmaxf(m, fabsf(v.z * rz));
    m = fmaxf(m, fabsf(v.w * rw));
  }
#pragma unroll
  for (int off = 32; off; off >>= 1) m = fmaxf(m, __shfl_xor(m, off));
  __shared__ float sm[4];
  if ((threadIdx.x & 63) == 0) sm[threadIdx.x >> 6] = m;
  __syncthreads();
  if (threadIdx.x == 0) {
    float mm = fmaxf(fmaxf(sm[0], sm[1]), fmaxf(sm[2], sm[3]));
    atomicMax(maxbits, __float_as_uint(mm));
  }
}

// ---------------------------------------------------------------------------
// Kernel 2: quantize x -> int8 packed. Same hoist: rinv = (1/s) * (1/d)
// computed once per thread; per-iter = 4 mul + 4 rndne + clamp + cvt + pack.
// ---------------------------------------------------------------------------
__global__ void quantize_x(const float4* __restrict__ x,
                           const float4* __restrict__ smooth4,
                           const unsigned int* __restrict__ maxbits,
                           int* __restrict__ xq, int n4) {
  const float d = __uint_as_float(*maxbits) / 127.0f + 1e-5f;
  const float inv = 1.0f / d;
  const int stride = gridDim.x * blockDim.x;
  const int g0 = blockIdx.x * blockDim.x + threadIdx.x;
  float4 s = smooth4[g0 & (K_TOT / 4 - 1)];
  const float rx = inv / s.x, ry = inv / s.y, rz = inv / s.z, rw = inv / s.w;
  for (int i = g0; i < n4; i += stride) {
    float4 v = x[i];
    int q0 = (int)fminf(fmaxf(rintf(v.x * rx), -128.0f), 127.0f);
    int q1 = (int)fminf(fmaxf(rintf(v.y * ry), -128.0f), 127.0f);
    int q2 = (int)fminf(fmaxf(rintf(v.z * rz), -128.0f), 127.0f);
    int q3 = (int)fminf(fmaxf(rintf(v.w * rw), -128.0f), 127.0f);
    xq[i] = (q0 & 0xff) | ((q1 & 0xff) << 8) | ((q2 & 0xff) << 16) | (q3 << 24);
  }
}

// ---------------------------------------------------------------------------
// Kernel 3: int8 GEMM, 256x256 tile, 64-B K-sub-tiles, 4-buffer / 3-deep
// counted-vmcnt pipeline, ONE barrier per sub-tile. MFMA = i32_32x32x32_i8
// (4404 TOPS ceiling vs 3944 for 16x16x64; half the instruction count).
//
// Per wave: 128x64 output = 4 (mf) x 2 (nf) frags of 32x32, acc 128 VGPR.
// A-frag lane map: row = l&31, k = (l>>5)*16 + j (16 contiguous bytes).
// B-frag: col = l&31, same k split.  C/D: col = l&31,
// row = (reg&3) + 8*(reg>>2) + 4*(l>>5)   [m74/m101, dtype-independent].
//
// Race-freedom (iteration s, reading buf[s&3]):
//   * stage targets buf[(s+3)&3] = buf[(s-1)&3]: reads completed before iter
//     s-1's end barrier (lgkmcnt(0) precedes it). -> no write-under-read.
//   * vmcnt(8) at iter s end: outstanding = 12 (s, s-1, s-2); completing to 8
//     drains the OLDEST 4 = sub-tile s+1's loads; barrier makes that global.
//     Induction base: prologue stages 0,1,2 then vmcnt(8) drains sub-tile 0.
//   * vmcnt never drains to 0 in the loop (T4).
//
// LDS swizzle (T2, 64-B rows, 8-lane ds_read_b128 grouping):
//   phys16Bslot = logical ^ ((row>>1)&3); slot8 = (row&1)*4 + phys.
//   Read windows (32-row frags): lanes 0-7 -> {0,4,1,5,2,6,3,7} etc: all
//   distinct (enumerated). Stage side: gcol = ((w&3) ^ ((w>>3)&3))*16 — the
//   same mapping R6 measured at SQ_LDS_BANK_CONFLICT == 0.
// ---------------------------------------------------------------------------
__global__ __launch_bounds__(512, 2) void gemm_i8(
    const int8_t* __restrict__ Aq,   // [M][K]
    const int8_t* __restrict__ Wt,   // [N][K]
    const unsigned int* __restrict__ maxbits,
    const float* __restrict__ wscale,  // [N]
    const float* __restrict__ bias,    // [N]
    float* __restrict__ out) {         // [M][N]
  __shared__ int8_t lds[4 * BUF_BYTES];

  const int tid = threadIdx.x;
  const int lane = tid & 63;
  const int wid = tid >> 6;      // 0..7
  const int l31 = lane & 31;
  const int lhi5 = lane >> 5;    // 0..1

  // T1: XCD-aware block swizzle. 512 blocks, 512 % 8 == 0 -> bijective.
  const int flat = blockIdx.y * gridDim.x + blockIdx.x;
  const int swz = (flat & 7) * 64 + (flat >> 3);
  const int m0 = (swz / (N_TOT / BN)) * BM;
  const int n0 = (swz % (N_TOT / BN)) * BN;

  const int wave_m = wid >> 2;   // 0..1  -> 128 rows
  const int wave_n = wid & 3;    // 0..3  -> 64 cols

  // ---- staging: per wave 2 A-chunks + 2 B-chunks, 1 KB each (16 rows x 64 B)
  const int row_l = lane >> 2;                             // row in chunk 0..15
  const int gcol = ((lane & 3) ^ ((lane >> 3) & 3)) << 4;  // pre-swizzled slot
  const int8_t* Abase = Aq + (size_t)m0 * K_TOT;           // uniform
  const int8_t* Bbase = Wt + (size_t)n0 * K_TOT;           // uniform
  int goff[2];
#pragma unroll
  for (int c = 0; c < 2; ++c) {
    int grow = (wid * 2 + c) * 16 + row_l;                 // 0..255
    goff[c] = grow * K_TOT + gcol;
  }

  auto stage = [&](int dstbuf, int koff) {
#pragma unroll
    for (int c = 0; c < 2; ++c) {
      __builtin_amdgcn_global_load_lds(
          (const __attribute__((address_space(1))) void*)(Abase + goff[c] + koff),
          (__attribute__((address_space(3))) void*)(lds + dstbuf * BUF_BYTES + (wid * 2 + c) * 1024),
          16, 0, 0);
      __builtin_amdgcn_global_load_lds(
          (const __attribute__((address_space(1))) void*)(Bbase + goff[c] + koff),
          (__attribute__((address_space(3))) void*)(lds + dstbuf * BUF_BYTES + A_SUB + (wid * 2 + c) * 1024),
          16, 0, 0);
    }
  };

  // ---- ds_read fragment addressing (swizzled, 64-B rows) ----
  const int f = (l31 >> 1) & 3;
  const int slot0 = ((0 + lhi5) ^ f) << 4;   // ks=0: logical slot = lhi5
  const int slot1 = ((2 + lhi5) ^ f) << 4;   // ks=1: logical slot = 2+lhi5
  const int aBase = (wave_m * 128 + l31) * SUB;
  const int bBase = (wave_n * 64 + l31) * SUB;

  // ---- prologue: stage sub-tiles 0,1,2; drain sub-tile 0 ----
  stage(0, 0);
  stage(1, SUB);
  stage(2, 2 * SUB);
  asm volatile("s_waitcnt vmcnt(8)" ::: "memory");
  __builtin_amdgcn_s_barrier();
  __builtin_amdgcn_sched_barrier(0);

  v16i acc[4][2] = {};

#pragma unroll 4
  for (int s = 0; s < NS; ++s) {
    const int buf = s & 3;
    const int8_t* Ab = lds + buf * BUF_BYTES;
    const int8_t* Bb = Ab + A_SUB;

    // prefetch sub-tile s+3 into the buffer drained at iter s-1
    const int ts = (s + 3 < NS) ? (s + 3) : (NS - 1);
    stage((s + 3) & 3, ts * SUB);

    // 12 ds_read_b128; compiler-counted lgkmcnt lets MFMA overlap them
    v4i a0[4], a1[4], b0[2], b1[2];
#pragma unroll
    for (int mf = 0; mf < 4; ++mf) {
      a0[mf] = *(const v4i*)(Ab + aBase + mf * 2048 + slot0);
      a1[mf] = *(const v4i*)(Ab + aBase + mf * 2048 + slot1);
    }
#pragma unroll
    for (int nf = 0; nf < 2; ++nf) {
      b0[nf] = *(const v4i*)(Bb + bBase + nf * 2048 + slot0);
      b1[nf] = *(const v4i*)(Bb + bBase + nf * 2048 + slot1);
    }

    __builtin_amdgcn_s_setprio(1);
#pragma unroll
    for (int mf = 0; mf < 4; ++mf)
#pragma unroll
      for (int nf = 0; nf < 2; ++nf)
        acc[mf][nf] = __builtin_amdgcn_mfma_i32_32x32x32_i8(a0[mf], b0[nf], acc[mf][nf], 0, 0, 0);
#pragma unroll
    for (int mf = 0; mf < 4; ++mf)
#pragma unroll
      for (int nf = 0; nf < 2; ++nf)
        acc[mf][nf] = __builtin_amdgcn_mfma_i32_32x32x32_i8(a1[mf], b1[nf], acc[mf][nf], 0, 0, 0);
    __builtin_amdgcn_s_setprio(0);
    __builtin_amdgcn_sched_barrier(0);

    asm volatile("s_waitcnt lgkmcnt(0)" ::: "memory");
    asm volatile("s_waitcnt vmcnt(8)" ::: "memory");
    __builtin_amdgcn_sched_barrier(0);
    __builtin_amdgcn_s_barrier();
    __builtin_amdgcn_sched_barrier(0);
  }

  // ---- epilogue: dequant + bias ----
  const float ascale = __uint_as_float(*maxbits) / 127.0f;
#pragma unroll
  for (int mf = 0; mf < 4; ++mf) {
#pragma unroll
    for (int nf = 0; nf < 2; ++nf) {
      const int ocol = n0 + wave_n * 64 + nf * 32 + l31;
      const float wsc = wscale[ocol] * ascale;
      const float bb = bias[ocol];
      const int rbase = m0 + wave_m * 128 + mf * 32 + 4 * lhi5;
#pragma unroll
      for (int reg = 0; reg < 16; ++reg) {
        const int orow = rbase + (reg & 3) + 8 * (reg >> 2);
        out[(size_t)orow * N_TOT + ocol] = (float)acc[mf][nf][reg] * wsc + bb;
      }
    }
  }
}

// ---------------------------------------------------------------------------
extern "C" void kernel_launch(void* const* d_in, const int* in_sizes, int n_in,
                              void* d_out, int out_size, void* d_ws, size_t ws_size,
                              hipStream_t stream) {
  const float* x = (const float*)d_in[0];
  const int* w32 = (const int*)d_in[1];        // int8 in reference, int32 on device
  const float* wscale = (const float*)d_in[2];
  const float* smooth = (const float*)d_in[3];
  const float* bias = (const float*)d_in[4];
  float* out = (float*)d_out;

  unsigned int* maxbits = (unsigned int*)d_ws;
  int8_t* xq = (int8_t*)d_ws + (1 << 20);                    // 32 MB
  int8_t* wq8 = xq + (size_t)M_TOT * K_TOT;                  // 16 MB

  hipMemsetAsync(d_ws, 0, 4, stream);  // zero the max accumulator each call

  const int nw4 = N_TOT * K_TOT / 4;
  const int n4 = M_TOT * K_TOT / 4;
  prep_reduce<<<2048, 256, 0, stream>>>((const int4*)w32, (int*)wq8, nw4,
                                        (const float4*)smooth, (const float4*)x,
                                        maxbits, n4);
  quantize_x<<<2048, 256, 0, stream>>>((const float4*)x, (const float4*)smooth,
                                       maxbits, (int*)xq, n4);

  dim3 grid(N_TOT / BN, M_TOT / BM);
  gemm_i8<<<grid, 512, 0, stream>>>(xq, wq8, maxbits, wscale, bias, out);
}